// Round 3
// baseline (778.691 us; speedup 1.0000x reference)
//
#include <hip/hip_runtime.h>
#include <hip/hip_bf16.h>
#include <cstdint>
#include <cstddef>

typedef __attribute__((ext_vector_type(8))) short short8;
typedef __attribute__((ext_vector_type(4))) float floatx4;
typedef __attribute__((ext_vector_type(4))) unsigned short ushort4_;

#define MFMA16(a, b, c) __builtin_amdgcn_mfma_f32_16x16x32_bf16((a), (b), (c), 0, 0, 0)

__device__ __forceinline__ unsigned short f2bf(float f) {
  __hip_bfloat16 h = __float2bfloat16(f);
  return *reinterpret_cast<unsigned short*>(&h);
}

__device__ __forceinline__ void gl_lds16(const void* g, void* lds) {
  __builtin_amdgcn_global_load_lds(
      (const __attribute__((address_space(1))) void*)g,
      (__attribute__((address_space(3))) void*)lds, 16, 0, 0);
}

// ---------------------------------------------------------------- cast kernel
__global__ void cast_f32_bf16(const float* __restrict__ in, __hip_bfloat16* __restrict__ out) {
  const int i = (blockIdx.x * 256 + threadIdx.x) * 4;
  const float4 v = *reinterpret_cast<const float4*>(in + i);
  ushort4_ o = { f2bf(v.x), f2bf(v.y), f2bf(v.z), f2bf(v.w) };
  *reinterpret_cast<ushort4_*>(out + i) = o;
}

// ---------------------------------------------------------------- GEMM  C = A * B^T + bias
template <int MODE>
__global__ __launch_bounds__(256, 2)
void gemm_bt(const __hip_bfloat16* __restrict__ A, const __hip_bfloat16* __restrict__ Bw,
             const float* __restrict__ bias, void* __restrict__ Cout,
             int M, int N, int K) {
  __shared__ __align__(16) __hip_bfloat16 As[128 * 32];
  __shared__ __align__(16) __hip_bfloat16 Bs[128 * 32];
  const int tid = threadIdx.x;
  const int w = tid >> 6, lane = tid & 63;
  const int g = lane >> 4, c16 = lane & 15;
  const int nbn = N >> 7;
  const int bm = blockIdx.x / nbn, bn = blockIdx.x % nbn;
  const int wr = w >> 1, wc = w & 1;

  floatx4 acc[4][4] = {};

  const int srow = lane >> 2;
  const int sseg = (lane & 3) * 8;
  const int nkt = K >> 5;
  for (int kt = 0; kt < nkt; ++kt) {
    const int kb = kt * 32;
#pragma unroll
    for (int i = 0; i < 2; ++i) {
      const int cidx = w + i * 4;
      const int row = cidx * 16 + srow;
      gl_lds16(A + (size_t)(bm * 128 + row) * K + kb + sseg, As + cidx * 512);
      gl_lds16(Bw + (size_t)(bn * 128 + row) * K + kb + sseg, Bs + cidx * 512);
    }
    __syncthreads();
    short8 af[4], bf[4];
#pragma unroll
    for (int m = 0; m < 4; ++m)
      af[m] = *reinterpret_cast<const short8*>(As + (wr * 64 + m * 16 + c16) * 32 + g * 8);
#pragma unroll
    for (int n = 0; n < 4; ++n)
      bf[n] = *reinterpret_cast<const short8*>(Bs + (wc * 64 + n * 16 + c16) * 32 + g * 8);
#pragma unroll
    for (int m = 0; m < 4; ++m)
#pragma unroll
      for (int n = 0; n < 4; ++n)
        acc[m][n] = MFMA16(af[m], bf[n], acc[m][n]);
    __syncthreads();
  }

#pragma unroll
  for (int n = 0; n < 4; ++n) {
    const int colg = bn * 128 + wc * 64 + n * 16 + c16;
    const float bv = bias[colg];
#pragma unroll
    for (int m = 0; m < 4; ++m) {
      const int rowg = bm * 128 + wr * 64 + m * 16 + g * 4;
      if (MODE == 0) {
        __hip_bfloat16* C = (__hip_bfloat16*)Cout;
#pragma unroll
        for (int j = 0; j < 4; ++j)
          C[(size_t)(rowg + j) * N + colg] = __float2bfloat16(acc[m][n][j] + bv);
      } else if (MODE == 1) {
        __hip_bfloat16* C = (__hip_bfloat16*)Cout;
        const int bb = rowg >> 11, t0 = rowg & 2047;
        ushort4_ pk = { f2bf(acc[m][n][0] + bv), f2bf(acc[m][n][1] + bv),
                        f2bf(acc[m][n][2] + bv), f2bf(acc[m][n][3] + bv) };
        *reinterpret_cast<ushort4_*>(C + ((size_t)bb * 2048 + colg) * 2048 + t0) = pk;
      } else {
        float* C = (float*)Cout;
#pragma unroll
        for (int j = 0; j < 4; ++j)
          C[(size_t)(rowg + j) * N + colg] = acc[m][n][j] + bv;
      }
    }
  }
}

// ---------------------------------------------------------------- flash attention v3 (causal)
// Q, K: [B*T][2048] bf16 (head h at column h*128).  Vt: [(b*16+h)*128 + d][t] bf16.
// 4 waves, QBLK=128 (32 q/wave), KBLK=64. K padded LDS, V XOR-swizzled LDS.
// T14 prefetch (K issued before QK^T, V before PV), T5 setprio, T13 defer-max.
__global__ __launch_bounds__(256, 3)
void attn_fwd3(const __hip_bfloat16* __restrict__ Q, const __hip_bfloat16* __restrict__ K,
               const __hip_bfloat16* __restrict__ Vt, __hip_bfloat16* __restrict__ ctx) {
  constexpr int T = 2048, C = 2048, D = 128;
  __shared__ __align__(16) __hip_bfloat16 Ks[64][136];    // padded: 272B stride
  __shared__ __align__(16) __hip_bfloat16 Vs[128][64];    // XOR-swizzled 16B slots
  __shared__ __align__(16) __hip_bfloat16 Pl[4][32][72];  // per-wave P re-layout
  // total LDS 52224 B -> 3 blocks/CU

  const int tid = threadIdx.x;
  const int w = tid >> 6, lane = tid & 63;
  const int g = lane >> 4, c16 = lane & 15;

  const int bid = blockIdx.x;
  const int swz = (bid & 7) * 128 + (bid >> 3);
  const int bh = swz >> 4, qb = 15 - (swz & 15);
  const int b = bh >> 4, h = bh & 15;
  const int wq = qb * 128 + w * 32;

  const __hip_bfloat16* Qh = Q + (size_t)b * T * C + h * D;
  const __hip_bfloat16* Kh = K + (size_t)b * T * C + h * D;
  const __hip_bfloat16* Vh = Vt + (size_t)bh * D * T;

  short8 qf[2][4];
#pragma unroll
  for (int m = 0; m < 2; ++m)
#pragma unroll
    for (int kk = 0; kk < 4; ++kk)
      qf[m][kk] = *reinterpret_cast<const short8*>(Qh + (size_t)(wq + m * 16 + c16) * C + kk * 32 + g * 8);

  floatx4 acc[2][8] = {};
  float mrow[2][4], lrow[2][4];
#pragma unroll
  for (int m = 0; m < 2; ++m)
#pragma unroll
    for (int j = 0; j < 4; ++j) { mrow[m][j] = -INFINITY; lrow[m][j] = 0.f; }

  const float scale = 0.08838834764831845f;
  const int krow = tid >> 4, kcol = (tid & 15) * 8;      // K staging
  const int vrow = tid >> 3;                              // V staging row within 32-chunk
  const int vslot = (tid & 7) ^ (vrow & 7);               // XOR-swizzled 16B slot
  const int vgcol = (tid & 7) * 8;                        // logical col in global Vt

  short8 kr[4], vr[4];
  auto gloadK = [&](int kb) {
#pragma unroll
    for (int p = 0; p < 4; ++p)
      kr[p] = *reinterpret_cast<const short8*>(Kh + (size_t)(kb + p * 16 + krow) * C + kcol);
  };
  auto gloadV = [&](int kb) {
#pragma unroll
    for (int p = 0; p < 4; ++p)
      vr[p] = *reinterpret_cast<const short8*>(Vh + (size_t)(p * 32 + vrow) * T + kb + vgcol);
  };

  __hip_bfloat16 (*Pq)[72] = Pl[w];
  const int nkt = qb * 2 + 2;
  gloadK(0);
  gloadV(0);

  for (int kt = 0; kt < nkt; ++kt) {
    const int kb = kt * 64;
    __syncthreads();                       // prior tile consumed; drains prefetch vmcnt
#pragma unroll
    for (int p = 0; p < 4; ++p)
      *reinterpret_cast<short8*>(&Ks[p * 16 + krow][kcol]) = kr[p];
#pragma unroll
    for (int p = 0; p < 4; ++p)
      *reinterpret_cast<short8*>(&Vs[p * 32 + vrow][vslot * 8]) = vr[p];
    __syncthreads();                       // staged tile visible

    const bool hasnext = (kt + 1 < nkt);
    const bool part = (kb <= wq + 31);     // wave-uniform participation
    if (hasnext) gloadK(kb + 64);          // prefetch: hides under QK^T+softmax

    floatx4 s[2][4] = {};
    if (part) {
      const bool needmask = (kb + 63 > wq);
      __builtin_amdgcn_s_setprio(1);
#pragma unroll
      for (int n = 0; n < 4; ++n)
#pragma unroll
        for (int kk = 0; kk < 4; ++kk) {
          short8 kf = *reinterpret_cast<const short8*>(&Ks[n * 16 + c16][kk * 32 + g * 8]);
          s[0][n] = MFMA16(qf[0][kk], kf, s[0][n]);
          s[1][n] = MFMA16(qf[1][kk], kf, s[1][n]);
        }
      __builtin_amdgcn_s_setprio(0);
      // ---- pass 1: scale+mask, per-row max
      float vmax[2][4];
#pragma unroll
      for (int m = 0; m < 2; ++m)
#pragma unroll
        for (int j = 0; j < 4; ++j) {
          const int qrow = wq + m * 16 + g * 4 + j;
#pragma unroll
          for (int n = 0; n < 4; ++n) {
            float a = s[m][n][j] * scale;
            if (needmask && (kb + n * 16 + c16 > qrow)) a = -INFINITY;
            s[m][n][j] = a;
          }
          float v = fmaxf(fmaxf(s[m][0][j], s[m][1][j]), fmaxf(s[m][2][j], s[m][3][j]));
#pragma unroll
          for (int o = 1; o < 16; o <<= 1) v = fmaxf(v, __shfl_xor(v, o));
          vmax[m][j] = v;
        }
      // ---- T13 defer-max: wave-uniform skip of O-rescale
      float grow = -INFINITY;
#pragma unroll
      for (int m = 0; m < 2; ++m)
#pragma unroll
        for (int j = 0; j < 4; ++j) grow = fmaxf(grow, vmax[m][j] - mrow[m][j]);
      const bool nore = __all(grow <= 8.0f);
      // ---- pass 2: exp, row-sum, P write (bounded by e^8 when deferred)
#pragma unroll
      for (int m = 0; m < 2; ++m)
#pragma unroll
        for (int j = 0; j < 4; ++j) {
          const float mn = nore ? mrow[m][j] : fmaxf(mrow[m][j], vmax[m][j]);
          float rs = 0.f;
#pragma unroll
          for (int n = 0; n < 4; ++n) {
            const float p = __expf(s[m][n][j] - mn);
            rs += p;
            Pq[m * 16 + g * 4 + j][n * 16 + c16] = __float2bfloat16(p);
          }
#pragma unroll
          for (int o = 1; o < 16; o <<= 1) rs += __shfl_xor(rs, o);
          if (nore) {
            lrow[m][j] += rs;
          } else {
            const float sc = __expf(mrow[m][j] - mn);
            lrow[m][j] = lrow[m][j] * sc + rs;
            mrow[m][j] = mn;
#pragma unroll
            for (int dt = 0; dt < 8; ++dt) acc[m][dt][j] *= sc;
          }
        }
    }
    if (hasnext) gloadV(kb + 64);          // prefetch: hides under PV
    if (part) {
      short8 ap[2][2];
#pragma unroll
      for (int m = 0; m < 2; ++m)
#pragma unroll
        for (int ks = 0; ks < 2; ++ks)
          ap[m][ks] = *reinterpret_cast<const short8*>(&Pq[m * 16 + c16][ks * 32 + g * 8]);
      __builtin_amdgcn_s_setprio(1);
#pragma unroll
      for (int dt = 0; dt < 8; ++dt)
#pragma unroll
        for (int ks = 0; ks < 2; ++ks) {
          const int pslot = ((ks * 4 + g) ^ (c16 & 7)) * 8;  // V swizzle on read
          short8 vf = *reinterpret_cast<const short8*>(&Vs[dt * 16 + c16][pslot]);
          acc[0][dt] = MFMA16(ap[0][ks], vf, acc[0][dt]);
          acc[1][dt] = MFMA16(ap[1][ks], vf, acc[1][dt]);
        }
      __builtin_amdgcn_s_setprio(0);
    }
  }

  // ---- epilogue
#pragma unroll
  for (int m = 0; m < 2; ++m)
#pragma unroll
    for (int j = 0; j < 4; ++j) {
      const float inv = 1.0f / lrow[m][j];
      const size_t row = (size_t)b * T + wq + m * 16 + g * 4 + j;
#pragma unroll
      for (int dt = 0; dt < 8; ++dt)
        ctx[row * C + h * D + dt * 16 + c16] = __float2bfloat16(acc[m][dt][j] * inv);
    }
}

// ---------------------------------------------------------------- launch
extern "C" void kernel_launch(void* const* d_in, const int* in_sizes, int n_in,
                              void* d_out, int out_size, void* d_ws, size_t ws_size,
                              hipStream_t stream) {
  const float* x  = (const float*)d_in[0];
  const float* Wq = (const float*)d_in[1];
  const float* bq = (const float*)d_in[2];
  const float* Wk = (const float*)d_in[3];
  const float* bk = (const float*)d_in[4];
  const float* Wv = (const float*)d_in[5];
  const float* bv = (const float*)d_in[6];
  const float* Wo = (const float*)d_in[7];
  const float* bo = (const float*)d_in[8];

  const int M = 8192, N = 2048, K = 2048;
  const size_t MB = 1u << 20;
  char* ws = (char*)d_ws;
  __hip_bfloat16* xb  = (__hip_bfloat16*)(ws);
  __hip_bfloat16* wqb = (__hip_bfloat16*)(ws + 32 * MB);
  __hip_bfloat16* wkb = (__hip_bfloat16*)(ws + 40 * MB);
  __hip_bfloat16* wvb = (__hip_bfloat16*)(ws + 48 * MB);
  __hip_bfloat16* wob = (__hip_bfloat16*)(ws + 56 * MB);
  __hip_bfloat16* Qb  = (__hip_bfloat16*)(ws + 64 * MB);
  __hip_bfloat16* Kb  = (__hip_bfloat16*)(ws + 96 * MB);
  __hip_bfloat16* Vtb = (__hip_bfloat16*)(ws + 128 * MB);
  if (ws_size < 160 * MB) return;

  cast_f32_bf16<<<(M * N) / 1024, 256, 0, stream>>>(x, xb);
  cast_f32_bf16<<<(N * K) / 1024, 256, 0, stream>>>(Wq, wqb);
  cast_f32_bf16<<<(N * K) / 1024, 256, 0, stream>>>(Wk, wkb);
  cast_f32_bf16<<<(N * K) / 1024, 256, 0, stream>>>(Wv, wvb);
  cast_f32_bf16<<<(N * K) / 1024, 256, 0, stream>>>(Wo, wob);

  const dim3 gg((M / 128) * (N / 128));
  gemm_bt<0><<<gg, 256, 0, stream>>>(xb, wqb, bq, Qb, M, N, K);
  gemm_bt<0><<<gg, 256, 0, stream>>>(xb, wkb, bk, Kb, M, N, K);
  gemm_bt<1><<<gg, 256, 0, stream>>>(xb, wvb, bv, Vtb, M, N, K);

  attn_fwd3<<<64 * 16, 256, 0, stream>>>(Qb, Kb, Vtb, xb);

  gemm_bt<2><<<gg, 256, 0, stream>>>(xb, wob, bo, d_out, M, N, K);
}

// Round 4
// 544.108 us; speedup vs baseline: 1.4311x; 1.4311x over previous
//
#include <hip/hip_runtime.h>
#include <hip/hip_bf16.h>
#include <cstdint>
#include <cstddef>

typedef __attribute__((ext_vector_type(8))) short short8;
typedef __attribute__((ext_vector_type(4))) short short4_;
typedef __attribute__((ext_vector_type(4))) float floatx4;
typedef __attribute__((ext_vector_type(4))) unsigned short ushort4_;

#define MFMA16(a, b, c) __builtin_amdgcn_mfma_f32_16x16x32_bf16((a), (b), (c), 0, 0, 0)

__device__ __forceinline__ unsigned short f2bf(float f) {
  __hip_bfloat16 h = __float2bfloat16(f);
  return *reinterpret_cast<unsigned short*>(&h);
}

__device__ __forceinline__ void gl_lds16(const void* g, void* lds) {
  __builtin_amdgcn_global_load_lds(
      (const __attribute__((address_space(1))) void*)g,
      (__attribute__((address_space(3))) void*)lds, 16, 0, 0);
}

// ---------------------------------------------------------------- cast kernel
__global__ void cast_f32_bf16(const float* __restrict__ in, __hip_bfloat16* __restrict__ out) {
  const int i = (blockIdx.x * 256 + threadIdx.x) * 4;
  const float4 v = *reinterpret_cast<const float4*>(in + i);
  ushort4_ o = { f2bf(v.x), f2bf(v.y), f2bf(v.z), f2bf(v.w) };
  *reinterpret_cast<ushort4_*>(out + i) = o;
}

// ---------------------------------------------------------------- GEMM  C = A * B^T + bias
template <int MODE>
__global__ __launch_bounds__(256, 2)
void gemm_bt(const __hip_bfloat16* __restrict__ A, const __hip_bfloat16* __restrict__ Bw,
             const float* __restrict__ bias, void* __restrict__ Cout,
             int M, int N, int K) {
  __shared__ __align__(16) __hip_bfloat16 As[128 * 32];
  __shared__ __align__(16) __hip_bfloat16 Bs[128 * 32];
  const int tid = threadIdx.x;
  const int w = tid >> 6, lane = tid & 63;
  const int g = lane >> 4, c16 = lane & 15;
  const int nbn = N >> 7;
  const int bm = blockIdx.x / nbn, bn = blockIdx.x % nbn;
  const int wr = w >> 1, wc = w & 1;

  floatx4 acc[4][4] = {};

  const int srow = lane >> 2;
  const int sseg = (lane & 3) * 8;
  const int nkt = K >> 5;
  for (int kt = 0; kt < nkt; ++kt) {
    const int kb = kt * 32;
#pragma unroll
    for (int i = 0; i < 2; ++i) {
      const int cidx = w + i * 4;
      const int row = cidx * 16 + srow;
      gl_lds16(A + (size_t)(bm * 128 + row) * K + kb + sseg, As + cidx * 512);
      gl_lds16(Bw + (size_t)(bn * 128 + row) * K + kb + sseg, Bs + cidx * 512);
    }
    __syncthreads();
    short8 af[4], bf[4];
#pragma unroll
    for (int m = 0; m < 4; ++m)
      af[m] = *reinterpret_cast<const short8*>(As + (wr * 64 + m * 16 + c16) * 32 + g * 8);
#pragma unroll
    for (int n = 0; n < 4; ++n)
      bf[n] = *reinterpret_cast<const short8*>(Bs + (wc * 64 + n * 16 + c16) * 32 + g * 8);
#pragma unroll
    for (int m = 0; m < 4; ++m)
#pragma unroll
      for (int n = 0; n < 4; ++n)
        acc[m][n] = MFMA16(af[m], bf[n], acc[m][n]);
    __syncthreads();
  }

#pragma unroll
  for (int n = 0; n < 4; ++n) {
    const int colg = bn * 128 + wc * 64 + n * 16 + c16;
    const float bv = bias[colg];
#pragma unroll
    for (int m = 0; m < 4; ++m) {
      const int rowg = bm * 128 + wr * 64 + m * 16 + g * 4;
      if (MODE == 0) {
        __hip_bfloat16* C = (__hip_bfloat16*)Cout;
#pragma unroll
        for (int j = 0; j < 4; ++j)
          C[(size_t)(rowg + j) * N + colg] = __float2bfloat16(acc[m][n][j] + bv);
      } else if (MODE == 1) {
        __hip_bfloat16* C = (__hip_bfloat16*)Cout;
        const int bb = rowg >> 11, t0 = rowg & 2047;
        ushort4_ pk = { f2bf(acc[m][n][0] + bv), f2bf(acc[m][n][1] + bv),
                        f2bf(acc[m][n][2] + bv), f2bf(acc[m][n][3] + bv) };
        *reinterpret_cast<ushort4_*>(C + ((size_t)bb * 2048 + colg) * 2048 + t0) = pk;
      } else {
        float* C = (float*)Cout;
#pragma unroll
        for (int j = 0; j < 4; ++j)
          C[(size_t)(rowg + j) * N + colg] = acc[m][n][j] + bv;
      }
    }
  }
}

// ---------------------------------------------------------------- flash attention v4 (causal)
// Swapped-operand structure: QK^T computed as MFMA(K,Q) -> S^T (col = q = c16),
// PV computed as MFMA(V,P) -> O^T (col = q = c16). Softmax stats are lane-local:
// row reduce = in-reg tree + 2 shfl_xor(16,32); rescale needs no redistribution.
// Q, K: [B*T][2048] bf16 (head h at col h*128).  Vt: [(b*16+h)*128 + d][t] bf16.
__global__ __launch_bounds__(256, 2)
void attn_fwd4(const __hip_bfloat16* __restrict__ Q, const __hip_bfloat16* __restrict__ K,
               const __hip_bfloat16* __restrict__ Vt, __hip_bfloat16* __restrict__ ctx) {
  constexpr int T = 2048, C = 2048, D = 128;
  __shared__ __align__(16) __hip_bfloat16 Ks[64][136];   // padded rows (conflict-free frags)
  __shared__ __align__(16) __hip_bfloat16 Vs[128][64];   // XOR-swizzled 16B slots
  __shared__ __align__(16) __hip_bfloat16 Pl[4][32][64]; // per-wave P, slot^c16 XOR layout
  // total LDS 50176 B

  const int tid = threadIdx.x;
  const int w = tid >> 6, lane = tid & 63;
  const int g = lane >> 4, c16 = lane & 15;

  const int bid = blockIdx.x;
  const int swz = (bid & 7) * 128 + (bid >> 3);
  const int bh = swz >> 4, qb = 15 - (swz & 15);
  const int b = bh >> 4, h = bh & 15;
  const int wq = qb * 128 + w * 32;

  const __hip_bfloat16* Qh = Q + (size_t)b * T * C + h * D;
  const __hip_bfloat16* Kh = K + (size_t)b * T * C + h * D;
  const __hip_bfloat16* Vh = Vt + (size_t)bh * D * T;

  short8 qf[2][4];
#pragma unroll
  for (int m = 0; m < 2; ++m)
#pragma unroll
    for (int kk = 0; kk < 4; ++kk)
      qf[m][kk] = *reinterpret_cast<const short8*>(Qh + (size_t)(wq + m * 16 + c16) * C + kk * 32 + g * 8);

  floatx4 acc[2][8] = {};                 // O^T frag: row = d_local = g*4+j, col = q = c16
  float mrow[2] = {-INFINITY, -INFINITY};
  float lrow[2] = {0.f, 0.f};

  const float scale = 0.08838834764831845f;
  const int krow = tid >> 4, kcol = (tid & 15) * 8;
  const int vrow = tid >> 3;
  const int vslot = (tid & 7) ^ (vrow & 7);
  const int vgcol = (tid & 7) * 8;

  short8 kr[4], vr[4];
  auto gloadK = [&](int kb) {
#pragma unroll
    for (int p = 0; p < 4; ++p)
      kr[p] = *reinterpret_cast<const short8*>(Kh + (size_t)(kb + p * 16 + krow) * C + kcol);
  };
  auto gloadV = [&](int kb) {
#pragma unroll
    for (int p = 0; p < 4; ++p)
      vr[p] = *reinterpret_cast<const short8*>(Vh + (size_t)(p * 32 + vrow) * T + kb + vgcol);
  };

  __hip_bfloat16 (*Pq)[64] = Pl[w];
  const int nkt = qb * 2 + 2;
  gloadK(0);
  gloadV(0);

  for (int kt = 0; kt < nkt; ++kt) {
    const int kb = kt * 64;
    __syncthreads();
#pragma unroll
    for (int p = 0; p < 4; ++p)
      *reinterpret_cast<short8*>(&Ks[p * 16 + krow][kcol]) = kr[p];
#pragma unroll
    for (int p = 0; p < 4; ++p)
      *reinterpret_cast<short8*>(&Vs[p * 32 + vrow][vslot * 8]) = vr[p];
    __syncthreads();

    const bool hasnext = (kt + 1 < nkt);
    const bool part = (kb <= wq + 31);
    if (hasnext) gloadK(kb + 64);

    if (part) {
      const bool needmask = (kb + 63 > wq);
      // ---- QK^T swapped: s[m][n] = S^T tile, row = k_local (g*4+j), col = q (c16)
      floatx4 s[2][4] = {};
      __builtin_amdgcn_s_setprio(1);
#pragma unroll
      for (int n = 0; n < 4; ++n)
#pragma unroll
        for (int kk = 0; kk < 4; ++kk) {
          short8 kf = *reinterpret_cast<const short8*>(&Ks[n * 16 + c16][kk * 32 + g * 8]);
          s[0][n] = MFMA16(kf, qf[0][kk], s[0][n]);
          s[1][n] = MFMA16(kf, qf[1][kk], s[1][n]);
        }
      __builtin_amdgcn_s_setprio(0);
      // ---- scale + mask + lane-local row max
      float vmax[2];
#pragma unroll
      for (int m = 0; m < 2; ++m) {
        const int q = wq + m * 16 + c16;
        float vm = -INFINITY;
#pragma unroll
        for (int n = 0; n < 4; ++n)
#pragma unroll
          for (int j = 0; j < 4; ++j) {
            float a = s[m][n][j] * scale;
            if (needmask && (kb + n * 16 + g * 4 + j > q)) a = -INFINITY;
            s[m][n][j] = a;
            vm = fmaxf(vm, a);
          }
        vm = fmaxf(vm, __shfl_xor(vm, 16));
        vm = fmaxf(vm, __shfl_xor(vm, 32));
        vmax[m] = vm;
      }
      // ---- T13 defer-max
      const float grow = fmaxf(vmax[0] - mrow[0], vmax[1] - mrow[1]);
      const bool nore = __all(grow <= 8.0f);
#pragma unroll
      for (int m = 0; m < 2; ++m) {
        const float mn = nore ? mrow[m] : fmaxf(mrow[m], vmax[m]);
        float rs = 0.f;
#pragma unroll
        for (int n = 0; n < 4; ++n) {
          float p0 = __expf(s[m][n][0] - mn), p1 = __expf(s[m][n][1] - mn);
          float p2 = __expf(s[m][n][2] - mn), p3 = __expf(s[m][n][3] - mn);
          rs += (p0 + p1) + (p2 + p3);
          ushort4_ pk = { f2bf(p0), f2bf(p1), f2bf(p2), f2bf(p3) };
          // logical 8B slot (4n+g) of row q, stored XOR'd: slot ^ c16  -> conflict-free
          *reinterpret_cast<ushort4_*>(&Pq[m * 16 + c16][((4 * n + g) ^ c16) * 4]) = pk;
        }
        rs += __shfl_xor(rs, 16);
        rs += __shfl_xor(rs, 32);
        if (nore) {
          lrow[m] += rs;
        } else {
          const float sc = __expf(mrow[m] - mn);
          lrow[m] = lrow[m] * sc + rs;
          mrow[m] = mn;
#pragma unroll
          for (int dt = 0; dt < 8; ++dt)
#pragma unroll
            for (int j = 0; j < 4; ++j) acc[m][dt][j] *= sc;
        }
      }
    }
    if (hasnext) gloadV(kb + 64);
    if (part) {
      // ---- P as B-operand: lane reads row q=c16, logical slots (8ks+2g,+1), XOR'd by c16
      short8 pb[2][2];
#pragma unroll
      for (int m = 0; m < 2; ++m)
#pragma unroll
        for (int ks = 0; ks < 2; ++ks) {
          short4_ lo = *reinterpret_cast<const short4_*>(&Pq[m * 16 + c16][((8 * ks + 2 * g) ^ c16) * 4]);
          short4_ hi = *reinterpret_cast<const short4_*>(&Pq[m * 16 + c16][((8 * ks + 2 * g + 1) ^ c16) * 4]);
          short8 r;
          r[0] = lo[0]; r[1] = lo[1]; r[2] = lo[2]; r[3] = lo[3];
          r[4] = hi[0]; r[5] = hi[1]; r[6] = hi[2]; r[7] = hi[3];
          pb[m][ks] = r;
        }
      __builtin_amdgcn_s_setprio(1);
#pragma unroll
      for (int dt = 0; dt < 8; ++dt)
#pragma unroll
        for (int ks = 0; ks < 2; ++ks) {
          const int pslot = ((ks * 4 + g) ^ (c16 & 7)) * 8;
          short8 vf = *reinterpret_cast<const short8*>(&Vs[dt * 16 + c16][pslot]);
          acc[0][dt] = MFMA16(vf, pb[0][ks], acc[0][dt]);
          acc[1][dt] = MFMA16(vf, pb[1][ks], acc[1][dt]);
        }
      __builtin_amdgcn_s_setprio(0);
    }
  }

  // ---- epilogue: O^T frag -> ctx[q][d]; lane writes 4 contiguous d (8B)
#pragma unroll
  for (int m = 0; m < 2; ++m) {
    const float inv = 1.0f / lrow[m];
    const size_t row = (size_t)b * T + wq + m * 16 + c16;
#pragma unroll
    for (int dt = 0; dt < 8; ++dt) {
      ushort4_ o = { f2bf(acc[m][dt][0] * inv), f2bf(acc[m][dt][1] * inv),
                     f2bf(acc[m][dt][2] * inv), f2bf(acc[m][dt][3] * inv) };
      *reinterpret_cast<ushort4_*>(ctx + row * C + h * D + dt * 16 + g * 4) = o;
    }
  }
}

// ---------------------------------------------------------------- launch
extern "C" void kernel_launch(void* const* d_in, const int* in_sizes, int n_in,
                              void* d_out, int out_size, void* d_ws, size_t ws_size,
                              hipStream_t stream) {
  const float* x  = (const float*)d_in[0];
  const float* Wq = (const float*)d_in[1];
  const float* bq = (const float*)d_in[2];
  const float* Wk = (const float*)d_in[3];
  const float* bk = (const float*)d_in[4];
  const float* Wv = (const float*)d_in[5];
  const float* bv = (const float*)d_in[6];
  const float* Wo = (const float*)d_in[7];
  const float* bo = (const float*)d_in[8];

  const int M = 8192, N = 2048, K = 2048;
  const size_t MB = 1u << 20;
  char* ws = (char*)d_ws;
  __hip_bfloat16* xb  = (__hip_bfloat16*)(ws);
  __hip_bfloat16* wqb = (__hip_bfloat16*)(ws + 32 * MB);
  __hip_bfloat16* wkb = (__hip_bfloat16*)(ws + 40 * MB);
  __hip_bfloat16* wvb = (__hip_bfloat16*)(ws + 48 * MB);
  __hip_bfloat16* wob = (__hip_bfloat16*)(ws + 56 * MB);
  __hip_bfloat16* Qb  = (__hip_bfloat16*)(ws + 64 * MB);
  __hip_bfloat16* Kb  = (__hip_bfloat16*)(ws + 96 * MB);
  __hip_bfloat16* Vtb = (__hip_bfloat16*)(ws + 128 * MB);
  if (ws_size < 160 * MB) return;

  cast_f32_bf16<<<(M * N) / 1024, 256, 0, stream>>>(x, xb);
  cast_f32_bf16<<<(N * K) / 1024, 256, 0, stream>>>(Wq, wqb);
  cast_f32_bf16<<<(N * K) / 1024, 256, 0, stream>>>(Wk, wkb);
  cast_f32_bf16<<<(N * K) / 1024, 256, 0, stream>>>(Wv, wvb);
  cast_f32_bf16<<<(N * K) / 1024, 256, 0, stream>>>(Wo, wob);

  const dim3 gg((M / 128) * (N / 128));
  gemm_bt<0><<<gg, 256, 0, stream>>>(xb, wqb, bq, Qb, M, N, K);
  gemm_bt<0><<<gg, 256, 0, stream>>>(xb, wkb, bk, Kb, M, N, K);
  gemm_bt<1><<<gg, 256, 0, stream>>>(xb, wvb, bv, Vtb, M, N, K);

  attn_fwd4<<<64 * 16, 256, 0, stream>>>(Qb, Kb, Vtb, xb);

  gemm_bt<2><<<gg, 256, 0, stream>>>(xb, wob, bo, d_out, M, N, K);
}

// Round 5
// 534.219 us; speedup vs baseline: 1.4576x; 1.0185x over previous
//
#include <hip/hip_runtime.h>
#include <hip/hip_bf16.h>
#include <cstdint>
#include <cstddef>

typedef __attribute__((ext_vector_type(8))) short short8;
typedef __attribute__((ext_vector_type(4))) short short4_;
typedef __attribute__((ext_vector_type(4))) float floatx4;
typedef __attribute__((ext_vector_type(4))) unsigned short ushort4_;

#define MFMA16(a, b, c) __builtin_amdgcn_mfma_f32_16x16x32_bf16((a), (b), (c), 0, 0, 0)

__device__ __forceinline__ unsigned short f2bf(float f) {
  __hip_bfloat16 h = __float2bfloat16(f);
  return *reinterpret_cast<unsigned short*>(&h);
}

__device__ __forceinline__ void gl_lds16(const void* g, void* lds) {
  __builtin_amdgcn_global_load_lds(
      (const __attribute__((address_space(1))) void*)g,
      (__attribute__((address_space(3))) void*)lds, 16, 0, 0);
}

// ---------------------------------------------------------------- cast kernel
__global__ void cast_f32_bf16(const float* __restrict__ in, __hip_bfloat16* __restrict__ out) {
  const int i = (blockIdx.x * 256 + threadIdx.x) * 4;
  const float4 v = *reinterpret_cast<const float4*>(in + i);
  ushort4_ o = { f2bf(v.x), f2bf(v.y), f2bf(v.z), f2bf(v.w) };
  *reinterpret_cast<ushort4_*>(out + i) = o;
}

// ---------------------------------------------------------------- GEMM v2: 256x256 tile, BK=32
// C = A * Bw^T + bias. A:[M][K] bf16, Bw:[N][K] bf16.
// 8 waves (2Mx4N), 4-slot LDS ring, counted-vmcnt deep prefetch (distance 3),
// T2 both-sides swizzle (linear LDS dest + inverse-swizzled global src + swizzled read).
// MODE 0: bf16 out row-major; MODE 1: bf16 transposed per-batch (Vt); MODE 2: f32 out.
template <int MODE>
__global__ __launch_bounds__(512, 2)
void gemm256(const __hip_bfloat16* __restrict__ Ap, const __hip_bfloat16* __restrict__ Bp,
             const float* __restrict__ bias, void* __restrict__ Cout,
             int M, int N, int K) {
  __shared__ __align__(16) __hip_bfloat16 SA[4][256 * 32];  // 64 KB: 4 ring slots of A-tile
  __shared__ __align__(16) __hip_bfloat16 SB[4][256 * 32];  // 64 KB

  const int tid = threadIdx.x;
  const int wid = tid >> 6, lane = tid & 63;
  const int wr = wid >> 2, wc = wid & 3;           // wave grid 2M x 4N
  const int g = lane >> 4, c16 = lane & 15;

  // XCD-chunked bijective swizzle: 256 blocks, 8 XCDs
  const int swzb = (blockIdx.x & 7) * 32 + (blockIdx.x >> 3);
  const int bm = swzb >> 3, bn = swzb & 7;         // 32 x 8 tile grid

  // staging geometry: per K-tile, per wave: 2 A-loads + 2 B-loads (16 rows each)
  const int srow = lane >> 2;                       // 0..15 row within 16-row slice
  const int slog = (lane & 3) ^ ((lane >> 3) & 3);  // inverse-swizzled logical 16B slot
  // read-side swizzle: elem offset within a row-block for (row c16, logical slot g)
  const int swz = c16 * 32 + (g ^ ((c16 >> 1) & 3)) * 8;

  floatx4 acc[8][4] = {};

  auto stage = [&](int kt) {
    const int kb = kt * 32;
    const int slot = kt & 3;
#pragma unroll
    for (int i = 0; i < 2; ++i) {
      const int rbase = i * 128 + wid * 16;         // wave-uniform row base
      gl_lds16(Ap + (size_t)(bm * 256 + rbase + srow) * K + kb + slog * 8,
               SA[slot] + rbase * 32);
      gl_lds16(Bp + (size_t)(bn * 256 + rbase + srow) * K + kb + slog * 8,
               SB[slot] + rbase * 32);
    }
  };

  auto compute = [&](int slot) {
    const __hip_bfloat16* sa = SA[slot];
    const __hip_bfloat16* sb = SB[slot];
    short8 af[8], bf[4];
#pragma unroll
    for (int m = 0; m < 8; ++m)
      af[m] = *reinterpret_cast<const short8*>(sa + wr * 4096 + m * 512 + swz);
#pragma unroll
    for (int n = 0; n < 4; ++n)
      bf[n] = *reinterpret_cast<const short8*>(sb + wc * 2048 + n * 512 + swz);
    __builtin_amdgcn_s_setprio(1);
#pragma unroll
    for (int m = 0; m < 8; ++m)
#pragma unroll
      for (int n = 0; n < 4; ++n)
        acc[m][n] = MFMA16(af[m], bf[n], acc[m][n]);
    __builtin_amdgcn_s_setprio(0);
  };

  const int nkt = K >> 5;                           // 64 K-tiles
  stage(0); stage(1); stage(2);                     // prologue: 12 loads in flight

  for (int kt = 0; kt < nkt - 3; ++kt) {
    asm volatile("s_waitcnt vmcnt(8)" ::: "memory");  // kt's 4 loads retired; 8 newer in flight
    __builtin_amdgcn_s_barrier();                     // publish slot kt&3; slot (kt+3)&3 free
    stage(kt + 3);
    compute(kt & 3);
  }
  asm volatile("s_waitcnt vmcnt(8)" ::: "memory");
  __builtin_amdgcn_s_barrier();
  compute((nkt - 3) & 3);
  asm volatile("s_waitcnt vmcnt(4)" ::: "memory");
  __builtin_amdgcn_s_barrier();
  compute((nkt - 2) & 3);
  asm volatile("s_waitcnt vmcnt(0)" ::: "memory");
  __builtin_amdgcn_s_barrier();
  compute((nkt - 1) & 3);

  // ---- epilogue: C row = bm*256 + wr*128 + m*16 + g*4 + j ; col = bn*256 + wc*64 + n*16 + c16
#pragma unroll
  for (int n = 0; n < 4; ++n) {
    const int colg = bn * 256 + wc * 64 + n * 16 + c16;
    const float bv = bias[colg];
#pragma unroll
    for (int m = 0; m < 8; ++m) {
      const int rowg = bm * 256 + wr * 128 + m * 16 + g * 4;
      if (MODE == 0) {
        __hip_bfloat16* C = (__hip_bfloat16*)Cout;
#pragma unroll
        for (int j = 0; j < 4; ++j)
          C[(size_t)(rowg + j) * N + colg] = __float2bfloat16(acc[m][n][j] + bv);
      } else if (MODE == 1) {
        __hip_bfloat16* C = (__hip_bfloat16*)Cout;
        const int bb = rowg >> 11, t0 = rowg & 2047;
        ushort4_ pk = { f2bf(acc[m][n][0] + bv), f2bf(acc[m][n][1] + bv),
                        f2bf(acc[m][n][2] + bv), f2bf(acc[m][n][3] + bv) };
        *reinterpret_cast<ushort4_*>(C + ((size_t)bb * 2048 + colg) * 2048 + t0) = pk;
      } else {
        float* C = (float*)Cout;
#pragma unroll
        for (int j = 0; j < 4; ++j)
          C[(size_t)(rowg + j) * N + colg] = acc[m][n][j] + bv;
      }
    }
  }
}

// ---------------------------------------------------------------- flash attention v4 (causal)
// Swapped-operand structure: QK^T as MFMA(K,Q) -> S^T (col=q=c16), PV as MFMA(V,P) -> O^T.
// Softmax stats lane-local; row reduce = in-reg tree + 2 shfl_xor(16,32).
__global__ __launch_bounds__(256, 2)
void attn_fwd4(const __hip_bfloat16* __restrict__ Q, const __hip_bfloat16* __restrict__ K,
               const __hip_bfloat16* __restrict__ Vt, __hip_bfloat16* __restrict__ ctx) {
  constexpr int T = 2048, C = 2048, D = 128;
  __shared__ __align__(16) __hip_bfloat16 Ks[64][136];
  __shared__ __align__(16) __hip_bfloat16 Vs[128][64];
  __shared__ __align__(16) __hip_bfloat16 Pl[4][32][64];

  const int tid = threadIdx.x;
  const int w = tid >> 6, lane = tid & 63;
  const int g = lane >> 4, c16 = lane & 15;

  const int bid = blockIdx.x;
  const int swz = (bid & 7) * 128 + (bid >> 3);
  const int bh = swz >> 4, qb = 15 - (swz & 15);
  const int b = bh >> 4, h = bh & 15;
  const int wq = qb * 128 + w * 32;

  const __hip_bfloat16* Qh = Q + (size_t)b * T * C + h * D;
  const __hip_bfloat16* Kh = K + (size_t)b * T * C + h * D;
  const __hip_bfloat16* Vh = Vt + (size_t)bh * D * T;

  short8 qf[2][4];
#pragma unroll
  for (int m = 0; m < 2; ++m)
#pragma unroll
    for (int kk = 0; kk < 4; ++kk)
      qf[m][kk] = *reinterpret_cast<const short8*>(Qh + (size_t)(wq + m * 16 + c16) * C + kk * 32 + g * 8);

  floatx4 acc[2][8] = {};
  float mrow[2] = {-INFINITY, -INFINITY};
  float lrow[2] = {0.f, 0.f};

  const float scale = 0.08838834764831845f;
  const int krow = tid >> 4, kcol = (tid & 15) * 8;
  const int vrow = tid >> 3;
  const int vslot = (tid & 7) ^ (vrow & 7);
  const int vgcol = (tid & 7) * 8;

  short8 kr[4], vr[4];
  auto gloadK = [&](int kb) {
#pragma unroll
    for (int p = 0; p < 4; ++p)
      kr[p] = *reinterpret_cast<const short8*>(Kh + (size_t)(kb + p * 16 + krow) * C + kcol);
  };
  auto gloadV = [&](int kb) {
#pragma unroll
    for (int p = 0; p < 4; ++p)
      vr[p] = *reinterpret_cast<const short8*>(Vh + (size_t)(p * 32 + vrow) * T + kb + vgcol);
  };

  __hip_bfloat16 (*Pq)[64] = Pl[w];
  const int nkt = qb * 2 + 2;
  gloadK(0);
  gloadV(0);

  for (int kt = 0; kt < nkt; ++kt) {
    const int kb = kt * 64;
    __syncthreads();
#pragma unroll
    for (int p = 0; p < 4; ++p)
      *reinterpret_cast<short8*>(&Ks[p * 16 + krow][kcol]) = kr[p];
#pragma unroll
    for (int p = 0; p < 4; ++p)
      *reinterpret_cast<short8*>(&Vs[p * 32 + vrow][vslot * 8]) = vr[p];
    __syncthreads();

    const bool hasnext = (kt + 1 < nkt);
    const bool part = (kb <= wq + 31);
    if (hasnext) gloadK(kb + 64);

    if (part) {
      const bool needmask = (kb + 63 > wq);
      floatx4 s[2][4] = {};
      __builtin_amdgcn_s_setprio(1);
#pragma unroll
      for (int n = 0; n < 4; ++n)
#pragma unroll
        for (int kk = 0; kk < 4; ++kk) {
          short8 kf = *reinterpret_cast<const short8*>(&Ks[n * 16 + c16][kk * 32 + g * 8]);
          s[0][n] = MFMA16(kf, qf[0][kk], s[0][n]);
          s[1][n] = MFMA16(kf, qf[1][kk], s[1][n]);
        }
      __builtin_amdgcn_s_setprio(0);
      float vmax[2];
#pragma unroll
      for (int m = 0; m < 2; ++m) {
        const int q = wq + m * 16 + c16;
        float vm = -INFINITY;
#pragma unroll
        for (int n = 0; n < 4; ++n)
#pragma unroll
          for (int j = 0; j < 4; ++j) {
            float a = s[m][n][j] * scale;
            if (needmask && (kb + n * 16 + g * 4 + j > q)) a = -INFINITY;
            s[m][n][j] = a;
            vm = fmaxf(vm, a);
          }
        vm = fmaxf(vm, __shfl_xor(vm, 16));
        vm = fmaxf(vm, __shfl_xor(vm, 32));
        vmax[m] = vm;
      }
      const float grow = fmaxf(vmax[0] - mrow[0], vmax[1] - mrow[1]);
      const bool nore = __all(grow <= 8.0f);
#pragma unroll
      for (int m = 0; m < 2; ++m) {
        const float mn = nore ? mrow[m] : fmaxf(mrow[m], vmax[m]);
        float rs = 0.f;
#pragma unroll
        for (int n = 0; n < 4; ++n) {
          float p0 = __expf(s[m][n][0] - mn), p1 = __expf(s[m][n][1] - mn);
          float p2 = __expf(s[m][n][2] - mn), p3 = __expf(s[m][n][3] - mn);
          rs += (p0 + p1) + (p2 + p3);
          ushort4_ pk = { f2bf(p0), f2bf(p1), f2bf(p2), f2bf(p3) };
          *reinterpret_cast<ushort4_*>(&Pq[m * 16 + c16][((4 * n + g) ^ c16) * 4]) = pk;
        }
        rs += __shfl_xor(rs, 16);
        rs += __shfl_xor(rs, 32);
        if (nore) {
          lrow[m] += rs;
        } else {
          const float sc = __expf(mrow[m] - mn);
          lrow[m] = lrow[m] * sc + rs;
          mrow[m] = mn;
#pragma unroll
          for (int dt = 0; dt < 8; ++dt)
#pragma unroll
            for (int j = 0; j < 4; ++j) acc[m][dt][j] *= sc;
        }
      }
    }
    if (hasnext) gloadV(kb + 64);
    if (part) {
      short8 pb[2][2];
#pragma unroll
      for (int m = 0; m < 2; ++m)
#pragma unroll
        for (int ks = 0; ks < 2; ++ks) {
          short4_ lo = *reinterpret_cast<const short4_*>(&Pq[m * 16 + c16][((8 * ks + 2 * g) ^ c16) * 4]);
          short4_ hi = *reinterpret_cast<const short4_*>(&Pq[m * 16 + c16][((8 * ks + 2 * g + 1) ^ c16) * 4]);
          short8 r;
          r[0] = lo[0]; r[1] = lo[1]; r[2] = lo[2]; r[3] = lo[3];
          r[4] = hi[0]; r[5] = hi[1]; r[6] = hi[2]; r[7] = hi[3];
          pb[m][ks] = r;
        }
      __builtin_amdgcn_s_setprio(1);
#pragma unroll
      for (int dt = 0; dt < 8; ++dt)
#pragma unroll
        for (int ks = 0; ks < 2; ++ks) {
          const int pslot = ((ks * 4 + g) ^ (c16 & 7)) * 8;
          short8 vf = *reinterpret_cast<const short8*>(&Vs[dt * 16 + c16][pslot]);
          acc[0][dt] = MFMA16(vf, pb[0][ks], acc[0][dt]);
          acc[1][dt] = MFMA16(vf, pb[1][ks], acc[1][dt]);
        }
      __builtin_amdgcn_s_setprio(0);
    }
  }

#pragma unroll
  for (int m = 0; m < 2; ++m) {
    const float inv = 1.0f / lrow[m];
    const size_t row = (size_t)b * T + wq + m * 16 + c16;
#pragma unroll
    for (int dt = 0; dt < 8; ++dt) {
      ushort4_ o = { f2bf(acc[m][dt][0] * inv), f2bf(acc[m][dt][1] * inv),
                     f2bf(acc[m][dt][2] * inv), f2bf(acc[m][dt][3] * inv) };
      *reinterpret_cast<ushort4_*>(ctx + row * C + h * D + dt * 16 + g * 4) = o;
    }
  }
}

// ---------------------------------------------------------------- launch
extern "C" void kernel_launch(void* const* d_in, const int* in_sizes, int n_in,
                              void* d_out, int out_size, void* d_ws, size_t ws_size,
                              hipStream_t stream) {
  const float* x  = (const float*)d_in[0];
  const float* Wq = (const float*)d_in[1];
  const float* bq = (const float*)d_in[2];
  const float* Wk = (const float*)d_in[3];
  const float* bk = (const float*)d_in[4];
  const float* Wv = (const float*)d_in[5];
  const float* bv = (const float*)d_in[6];
  const float* Wo = (const float*)d_in[7];
  const float* bo = (const float*)d_in[8];

  const int M = 8192, N = 2048, K = 2048;
  const size_t MB = 1u << 20;
  char* ws = (char*)d_ws;
  __hip_bfloat16* xb  = (__hip_bfloat16*)(ws);
  __hip_bfloat16* wqb = (__hip_bfloat16*)(ws + 32 * MB);
  __hip_bfloat16* wkb = (__hip_bfloat16*)(ws + 40 * MB);
  __hip_bfloat16* wvb = (__hip_bfloat16*)(ws + 48 * MB);
  __hip_bfloat16* wob = (__hip_bfloat16*)(ws + 56 * MB);
  __hip_bfloat16* Qb  = (__hip_bfloat16*)(ws + 64 * MB);
  __hip_bfloat16* Kb  = (__hip_bfloat16*)(ws + 96 * MB);
  __hip_bfloat16* Vtb = (__hip_bfloat16*)(ws + 128 * MB);
  if (ws_size < 160 * MB) return;

  cast_f32_bf16<<<(M * N) / 1024, 256, 0, stream>>>(x, xb);
  cast_f32_bf16<<<(N * K) / 1024, 256, 0, stream>>>(Wq, wqb);
  cast_f32_bf16<<<(N * K) / 1024, 256, 0, stream>>>(Wk, wkb);
  cast_f32_bf16<<<(N * K) / 1024, 256, 0, stream>>>(Wv, wvb);
  cast_f32_bf16<<<(N * K) / 1024, 256, 0, stream>>>(Wo, wob);

  const dim3 gg((M / 256) * (N / 256));   // 256 blocks = 1 per CU
  gemm256<0><<<gg, 512, 0, stream>>>(xb, wqb, bq, Qb, M, N, K);
  gemm256<0><<<gg, 512, 0, stream>>>(xb, wkb, bk, Kb, M, N, K);
  gemm256<1><<<gg, 512, 0, stream>>>(xb, wvb, bv, Vtb, M, N, K);

  attn_fwd4<<<64 * 16, 256, 0, stream>>>(Qb, Kb, Vtb, xb);

  gemm256<2><<<gg, 512, 0, stream>>>(xb, wob, bo, d_out, M, N, K);
}